// Round 7
// baseline (209.201 us; speedup 1.0000x reference)
//
#include <hip/hip_runtime.h>
#include <math.h>

#define IH 1024
#define IW 1024
#define NPIX (IH * IW)

// ---------------- Stage 1+2+3 fused: gray -> Sobel -> NMS -> bit-packed ----------
// Block = 256 threads = 4 waves; tile = 16 rows x 64 cols.  Each wave's 64 lanes
// are one row of 64 columns, so __ballot emits the u64 row-word directly.
__global__ __launch_bounds__(256) void k_fused(const float* __restrict__ x,
                                               unsigned long long* __restrict__ Sp,
                                               unsigned long long* __restrict__ Wp) {
    __shared__ float g[20][72];   // gray tile, origin (-2,-2) of interior
    __shared__ float m[18][68];   // mag tile,  origin (-1,-1) of interior
    const int bx = blockIdx.x & 15, by = blockIdx.x >> 4;
    const int tid = threadIdx.x;
    const int gi0 = by * 16 - 2, gj0 = bx * 64 - 2;

    for (int e = tid; e < 20 * 68; e += 256) {
        int ly = e / 68, lx = e - ly * 68;
        int gy = gi0 + ly, gxc = gj0 + lx;
        float v = 0.f;
        if ((unsigned)gy < (unsigned)IH && (unsigned)gxc < (unsigned)IW) {
            int p = gy * IW + gxc;
            float r = x[p], gg = x[NPIX + p], b = x[2 * NPIX + p];
            v = __fadd_rn(__fadd_rn(__fmul_rn(r, 0.2989f), __fmul_rn(gg, 0.587f)),
                          __fmul_rn(b, 0.114f));
        }
        g[ly][lx] = v;
    }
    __syncthreads();

    for (int e = tid; e < 18 * 66; e += 256) {
        int ly = e / 66, lx = e - ly * 66;
        float a00 = g[ly][lx],   a01 = g[ly][lx+1],   a02 = g[ly][lx+2];
        float a10 = g[ly+1][lx],                      a12 = g[ly+1][lx+2];
        float a20 = g[ly+2][lx], a21 = g[ly+2][lx+1], a22 = g[ly+2][lx+2];
        float gx = __fmul_rn(-1.f, a00);
        gx = __fadd_rn(gx, a02);
        gx = __fadd_rn(gx, __fmul_rn(-2.f, a10));
        gx = __fadd_rn(gx, __fmul_rn(2.f, a12));
        gx = __fadd_rn(gx, __fmul_rn(-1.f, a20));
        gx = __fadd_rn(gx, a22);
        float gy = a00;
        gy = __fadd_rn(gy, __fmul_rn(2.f, a01));
        gy = __fadd_rn(gy, a02);
        gy = __fadd_rn(gy, __fmul_rn(-1.f, a20));
        gy = __fadd_rn(gy, __fmul_rn(-2.f, a21));
        gy = __fadd_rn(gy, __fmul_rn(-1.f, a22));
        m[ly][lx] = __fsqrt_rn(__fadd_rn(__fmul_rn(gx, gx), __fmul_rn(gy, gy)));
    }
    __syncthreads();

    const int lane = tid & 63;
    const int wv = tid >> 6;
    #pragma unroll
    for (int rr = 0; rr < 4; ++rr) {
        int ti = wv * 4 + rr;
        int i = by * 16 + ti, j = bx * 64 + lane;
        float a00 = g[ti+1][lane+1], a01 = g[ti+1][lane+2], a02 = g[ti+1][lane+3];
        float a10 = g[ti+2][lane+1],                         a12 = g[ti+2][lane+3];
        float a20 = g[ti+3][lane+1], a21 = g[ti+3][lane+2], a22 = g[ti+3][lane+3];
        float gx = __fmul_rn(-1.f, a00);
        gx = __fadd_rn(gx, a02);
        gx = __fadd_rn(gx, __fmul_rn(-2.f, a10));
        gx = __fadd_rn(gx, __fmul_rn(2.f, a12));
        gx = __fadd_rn(gx, __fmul_rn(-1.f, a20));
        gx = __fadd_rn(gx, a22);
        float gy = a00;
        gy = __fadd_rn(gy, __fmul_rn(2.f, a01));
        gy = __fadd_rn(gy, a02);
        gy = __fadd_rn(gy, __fmul_rn(-1.f, a20));
        gy = __fadd_rn(gy, __fmul_rn(-2.f, a21));
        gy = __fadd_rn(gy, __fmul_rn(-1.f, a22));

        float ai = __fmul_rn(atan2f(gy, gx), 57.295779513082320876798154814105f);
        float c = m[ti+1][lane+1];
        float n1, n2;
        if (ai < -22.5f || ai >= 157.5f)      { n1 = m[ti+1][lane];   n2 = m[ti+1][lane+2]; }
        else if (ai < 22.5f)                  { n1 = m[ti][lane+1];   n2 = m[ti+2][lane+1]; }
        else if (ai < 67.5f)                  { n1 = m[ti][lane];     n2 = m[ti+2][lane+2]; }
        else if (ai < 112.5f)                 { n1 = m[ti][lane+1];   n2 = m[ti+2][lane+1]; }
        else                                  { n1 = m[ti][lane+2];   n2 = m[ti+2][lane];   }
        bool border = (i == 0) | (i == IH - 1) | (j == 0) | (j == IW - 1);
        bool keep = (c >= n1) && (c >= n2);
        float supp = keep ? c : 0.f;
        bool sb = !border && (supp >= 50.f);
        bool wb = !border && (supp >= 20.f) && !(supp >= 50.f);
        unsigned long long bs = __ballot(sb);
        unsigned long long bw = __ballot(wb);
        if (lane == 0) {
            Sp[i * 16 + bx] = bs;
            Wp[i * 16 + bx] = bw;
        }
    }
}

// Opaque load: hides pointer provenance so the load can't be sunk past the
// in-loop Sp stores nor rematerialized -> the value must stay live in a VGPR.
__device__ __forceinline__ unsigned int oload(const unsigned int* p, int off, int k) {
    const unsigned int* q = p + off;
    asm volatile("" : "+s"(q));
    return q[k];
}

// ---------------- Stage 4: single-wave tracker ----------------
#define TRACK_BODY(d, SRD, SWR, WRD) {                                          \
    const int i = base + d;                                                     \
    /* ---- serial chain head ---- */                                           \
    unsigned int hxp = (prevU << 1) | prevU | ((prevU >> 1) | crp);             \
    unsigned int seed = hxp | STAT;                                             \
    unsigned int P = WRD;                                                       \
    unsigned int G = SCc | (P & seed);                                          \
    unsigned int A = G | P;                                                     \
    unsigned int AXG = A ^ G;                                                   \
    unsigned int s1v = A + G;                                                   \
    unsigned long long gm = __ballot(s1v < A) & 0xFFFFFFFFull;                  \
    unsigned long long pm = __ballot(s1v == 0xFFFFFFFFu) & 0xFFFFFFFFull;       \
    unsigned long long G0 = __ballot((G & 1u) != 0u);                           \
    unsigned long long P0 = __ballot((P & 1u) != 0u);                           \
    __builtin_amdgcn_sched_barrier(0);                                          \
    /* ---- independent: next row's static seed + prefetch + store ---- */      \
    unsigned int SN2 = SRD;                                                     \
    unsigned long long mhi = __ballot((SN2 >> 31) != 0u);                       \
    unsigned long long mlo2 = __ballot((SN2 & 1u) != 0u);                       \
    unsigned int ltN = (((unsigned int)(mhi << 1)) >> k) & 1u;                  \
    unsigned int rtN = ((((unsigned int)(mlo2 >> 1)) >> k) & 1u) << 31;         \
    unsigned int rxN = SN2 | (SN2 >> 1) | rtN;                                  \
    unsigned int hxN = rxN | (SN2 << 1) | ltN;                                  \
    unsigned int nSTAT = rxA | hxN;                                             \
    { int srow = i + 17; if (srow > 1023) srow = 1023;                          \
      int wrow = i + 16; if (wrow > 1023) wrow = 1023;                          \
      SWR = oload(Sp, srow * 32, k);                                            \
      WRD = oload(Wp, wrow * 32, k); }                                          \
    if (i >= 2 && i <= 1023) Sp[(i - 1) * 32 + k] = prevU;                      \
    __builtin_amdgcn_sched_barrier(0);                                          \
    /* ---- resolve cross-word carries ---- */                                  \
    unsigned long long aa = gm | pm;                                            \
    unsigned long long ssum = aa + gm;                                          \
    unsigned long long cvw = ssum ^ aa ^ gm;                                    \
    unsigned long long mlo_o = G0 | (P0 & cvw);                                 \
    unsigned int cin = (((unsigned int)cvw) >> k) & 1u;                         \
    unsigned int ovb = ((((unsigned int)(cvw >> 1)) >> k) & 1u) << 31;          \
    unsigned int s2 = s1v + cin;                                                \
    unsigned int outv = ((s2 ^ AXG) >> 1) | ovb;                                \
    unsigned int rtP = ((((unsigned int)(mlo_o >> 1)) >> k) & 1u) << 31;        \
    crp = cin | rtP;                                                            \
    prevU = outv;                                                               \
    SCc = SA; SA = SN2; STAT = nSTAT; rxA = rxN;                                \
}

// ONE wave on the whole GPU: tell scheduler+allocator that occupancy 1 is all
// we need, so it stops spilling the pipeline to scratch to hit a high
// occupancy target (R4/R5 failure mode: VGPR_Count stuck at 28-32).
__global__ __launch_bounds__(64, 1) __attribute__((amdgpu_waves_per_eu(1, 1)))
void k_track(unsigned int* __restrict__ Sp,
             const unsigned int* __restrict__ Wp) {
    const int k = threadIdx.x & 31;

    unsigned int ss0, ss1, ss2, ss3, ss4, ss5, ss6, ss7,
                 ss8, ss9, ss10, ss11, ss12, ss13, ss14, ss15;
    unsigned int ww0, ww1, ww2, ww3, ww4, ww5, ww6, ww7,
                 ww8, ww9, ww10, ww11, ww12, ww13, ww14, ww15;

    unsigned int SCc = oload(Sp, 1 * 32, k);
    unsigned int SA  = oload(Sp, 2 * 32, k);
    ss3 = oload(Sp, 3 * 32, k);   ss4 = oload(Sp, 4 * 32, k);
    ss5 = oload(Sp, 5 * 32, k);   ss6 = oload(Sp, 6 * 32, k);
    ss7 = oload(Sp, 7 * 32, k);   ss8 = oload(Sp, 8 * 32, k);
    ss9 = oload(Sp, 9 * 32, k);   ss10 = oload(Sp, 10 * 32, k);
    ss11 = oload(Sp, 11 * 32, k); ss12 = oload(Sp, 12 * 32, k);
    ss13 = oload(Sp, 13 * 32, k); ss14 = oload(Sp, 14 * 32, k);
    ss15 = oload(Sp, 15 * 32, k); ss0 = oload(Sp, 16 * 32, k);
    ss1 = oload(Sp, 17 * 32, k);  ss2 = 0u;
    ww1 = oload(Wp, 1 * 32, k);   ww2 = oload(Wp, 2 * 32, k);
    ww3 = oload(Wp, 3 * 32, k);   ww4 = oload(Wp, 4 * 32, k);
    ww5 = oload(Wp, 5 * 32, k);   ww6 = oload(Wp, 6 * 32, k);
    ww7 = oload(Wp, 7 * 32, k);   ww8 = oload(Wp, 8 * 32, k);
    ww9 = oload(Wp, 9 * 32, k);   ww10 = oload(Wp, 10 * 32, k);
    ww11 = oload(Wp, 11 * 32, k); ww12 = oload(Wp, 12 * 32, k);
    ww13 = oload(Wp, 13 * 32, k); ww14 = oload(Wp, 14 * 32, k);
    ww15 = oload(Wp, 15 * 32, k); ww0 = oload(Wp, 16 * 32, k);

    unsigned long long mSC_lo = __ballot((SCc & 1u) != 0u);
    unsigned long long mSA_lo = __ballot((SA & 1u) != 0u);
    unsigned long long mSA_hi = __ballot((SA >> 31) != 0u);
    unsigned int rtC = ((((unsigned int)(mSC_lo >> 1)) >> k) & 1u) << 31;
    unsigned int rxC = SCc | (SCc >> 1) | rtC;
    unsigned int rtA0 = ((((unsigned int)(mSA_lo >> 1)) >> k) & 1u) << 31;
    unsigned int rxA = SA | (SA >> 1) | rtA0;          // Rx(S_2), carried forward
    unsigned int ltA = (((unsigned int)(mSA_hi << 1)) >> k) & 1u;
    unsigned int hxA = rxA | (SA << 1) | ltA;
    unsigned int STAT = rxC | hxA;
    unsigned int prevU = 0u, crp = 0u;

    #pragma unroll 1
    for (int b = 0; b < 64; ++b) {
        const int base = 1 + b * 16;
        TRACK_BODY(0,  ss3,  ss2,  ww1)
        TRACK_BODY(1,  ss4,  ss3,  ww2)
        TRACK_BODY(2,  ss5,  ss4,  ww3)
        TRACK_BODY(3,  ss6,  ss5,  ww4)
        TRACK_BODY(4,  ss7,  ss6,  ww5)
        TRACK_BODY(5,  ss8,  ss7,  ww6)
        TRACK_BODY(6,  ss9,  ss8,  ww7)
        TRACK_BODY(7,  ss10, ss9,  ww8)
        TRACK_BODY(8,  ss11, ss10, ww9)
        TRACK_BODY(9,  ss12, ss11, ww10)
        TRACK_BODY(10, ss13, ss12, ww11)
        TRACK_BODY(11, ss14, ss13, ww12)
        TRACK_BODY(12, ss15, ss14, ww13)
        TRACK_BODY(13, ss0,  ss15, ww14)
        TRACK_BODY(14, ss1,  ss0,  ww15)
        TRACK_BODY(15, ss2,  ss1,  ww0)
    }
}

// ---------------- Stage 5: unpack bits -> float ----------------
__global__ void k_unpack(const unsigned int* __restrict__ Sp,
                         float* __restrict__ out) {
    int idx = blockIdx.x * blockDim.x + threadIdx.x;
    if (idx >= NPIX) return;
    out[idx] = ((Sp[idx >> 5] >> (idx & 31)) & 1u) ? 1.f : 0.f;
}

extern "C" void kernel_launch(void* const* d_in, const int* in_sizes, int n_in,
                              void* d_out, int out_size, void* d_ws, size_t ws_size,
                              hipStream_t stream) {
    const float* x = (const float*)d_in[0];
    float* out = (float*)d_out;
    char* ws = (char*)d_ws;

    unsigned long long* Sp = (unsigned long long*)(ws);
    unsigned long long* Wp = (unsigned long long*)(ws + 128u * 1024u);

    k_fused<<<1024, 256, 0, stream>>>(x, Sp, Wp);
    k_track<<<1, 64, 0, stream>>>((unsigned int*)Sp, (const unsigned int*)Wp);
    k_unpack<<<4096, 256, 0, stream>>>((const unsigned int*)Sp, out);
}

// Round 8
// 181.408 us; speedup vs baseline: 1.1532x; 1.1532x over previous
//
#include <hip/hip_runtime.h>
#include <math.h>

#define IH 1024
#define IW 1024
#define NPIX (IH * IW)

// ---------------- Stage 1+2+3 fused: gray -> Sobel -> NMS -> bit-packed ----------
__global__ __launch_bounds__(256) void k_fused(const float* __restrict__ x,
                                               unsigned long long* __restrict__ Sp,
                                               unsigned long long* __restrict__ Wp) {
    __shared__ float g[20][72];
    __shared__ float m[18][68];
    const int bx = blockIdx.x & 15, by = blockIdx.x >> 4;
    const int tid = threadIdx.x;
    const int gi0 = by * 16 - 2, gj0 = bx * 64 - 2;

    for (int e = tid; e < 20 * 68; e += 256) {
        int ly = e / 68, lx = e - ly * 68;
        int gy = gi0 + ly, gxc = gj0 + lx;
        float v = 0.f;
        if ((unsigned)gy < (unsigned)IH && (unsigned)gxc < (unsigned)IW) {
            int p = gy * IW + gxc;
            float r = x[p], gg = x[NPIX + p], b = x[2 * NPIX + p];
            v = __fadd_rn(__fadd_rn(__fmul_rn(r, 0.2989f), __fmul_rn(gg, 0.587f)),
                          __fmul_rn(b, 0.114f));
        }
        g[ly][lx] = v;
    }
    __syncthreads();

    for (int e = tid; e < 18 * 66; e += 256) {
        int ly = e / 66, lx = e - ly * 66;
        float a00 = g[ly][lx],   a01 = g[ly][lx+1],   a02 = g[ly][lx+2];
        float a10 = g[ly+1][lx],                      a12 = g[ly+1][lx+2];
        float a20 = g[ly+2][lx], a21 = g[ly+2][lx+1], a22 = g[ly+2][lx+2];
        float gx = __fmul_rn(-1.f, a00);
        gx = __fadd_rn(gx, a02);
        gx = __fadd_rn(gx, __fmul_rn(-2.f, a10));
        gx = __fadd_rn(gx, __fmul_rn(2.f, a12));
        gx = __fadd_rn(gx, __fmul_rn(-1.f, a20));
        gx = __fadd_rn(gx, a22);
        float gy = a00;
        gy = __fadd_rn(gy, __fmul_rn(2.f, a01));
        gy = __fadd_rn(gy, a02);
        gy = __fadd_rn(gy, __fmul_rn(-1.f, a20));
        gy = __fadd_rn(gy, __fmul_rn(-2.f, a21));
        gy = __fadd_rn(gy, __fmul_rn(-1.f, a22));
        m[ly][lx] = __fsqrt_rn(__fadd_rn(__fmul_rn(gx, gx), __fmul_rn(gy, gy)));
    }
    __syncthreads();

    const int lane = tid & 63;
    const int wv = tid >> 6;
    #pragma unroll
    for (int rr = 0; rr < 4; ++rr) {
        int ti = wv * 4 + rr;
        int i = by * 16 + ti, j = bx * 64 + lane;
        float a00 = g[ti+1][lane+1], a01 = g[ti+1][lane+2], a02 = g[ti+1][lane+3];
        float a10 = g[ti+2][lane+1],                         a12 = g[ti+2][lane+3];
        float a20 = g[ti+3][lane+1], a21 = g[ti+3][lane+2], a22 = g[ti+3][lane+3];
        float gx = __fmul_rn(-1.f, a00);
        gx = __fadd_rn(gx, a02);
        gx = __fadd_rn(gx, __fmul_rn(-2.f, a10));
        gx = __fadd_rn(gx, __fmul_rn(2.f, a12));
        gx = __fadd_rn(gx, __fmul_rn(-1.f, a20));
        gx = __fadd_rn(gx, a22);
        float gy = a00;
        gy = __fadd_rn(gy, __fmul_rn(2.f, a01));
        gy = __fadd_rn(gy, a02);
        gy = __fadd_rn(gy, __fmul_rn(-1.f, a20));
        gy = __fadd_rn(gy, __fmul_rn(-2.f, a21));
        gy = __fadd_rn(gy, __fmul_rn(-1.f, a22));

        float ai = __fmul_rn(atan2f(gy, gx), 57.295779513082320876798154814105f);
        float c = m[ti+1][lane+1];
        float n1, n2;
        if (ai < -22.5f || ai >= 157.5f)      { n1 = m[ti+1][lane];   n2 = m[ti+1][lane+2]; }
        else if (ai < 22.5f)                  { n1 = m[ti][lane+1];   n2 = m[ti+2][lane+1]; }
        else if (ai < 67.5f)                  { n1 = m[ti][lane];     n2 = m[ti+2][lane+2]; }
        else if (ai < 112.5f)                 { n1 = m[ti][lane+1];   n2 = m[ti+2][lane+1]; }
        else                                  { n1 = m[ti][lane+2];   n2 = m[ti+2][lane];   }
        bool border = (i == 0) | (i == IH - 1) | (j == 0) | (j == IW - 1);
        bool keep = (c >= n1) && (c >= n2);
        float supp = keep ? c : 0.f;
        bool sb = !border && (supp >= 50.f);
        bool wb = !border && (supp >= 20.f) && !(supp >= 50.f);
        unsigned long long bs = __ballot(sb);
        unsigned long long bw = __ballot(wb);
        if (lane == 0) {
            Sp[i * 16 + bx] = bs;
            Wp[i * 16 + bx] = bw;
        }
    }
}

// ---------------- Stage 4: producer/consumer 2-wave tracker ----------------
// Wave 1 (producer): streams original S/W rows, computes the static seed STAT,
// deposits {W, S, STAT} into a 128-row LDS ring, publishes prodRow.
// Wave 0 (consumer): per row, 3 ds_reads (prefetched 4 rows ahead) + the
// serial carry chain + 1 global store.  No global loads on the chain.

// producer: one row's static work.  RS = S_{i+1}, RW = W_i; rolls SA=S_i, mloA.
#define PBODY(j, RS, RW) {                                                      \
    unsigned long long mhiN = __ballot((RS >> 31) != 0u);                       \
    unsigned long long mloN = __ballot((RS & 1u) != 0u);                        \
    unsigned int rtC = ((((unsigned int)(mloA >> 1)) >> k) & 1u) << 31;         \
    unsigned int rxC = SA | (SA >> 1) | rtC;                                    \
    unsigned int ltN = (((unsigned int)(mhiN << 1)) >> k) & 1u;                 \
    unsigned int rtN = ((((unsigned int)(mloN >> 1)) >> k) & 1u) << 31;         \
    unsigned int hxN = RS | (RS << 1) | (RS >> 1) | ltN | rtN;                  \
    unsigned int STAT = rxC | hxN;                                              \
    int sl = (gbase + j) & 127;                                                 \
    lW[sl][k] = RW; lS[sl][k] = SA; lT[sl][k] = STAT;                           \
    SA = RS; mloA = mloN;                                                       \
}

#define PLOAD(gb, j, RS, RW) {                                                  \
    int rs = (gb) + (j) + 1; if (rs > 1023) rs = 1023;                          \
    int rw = (gb) + (j);     if (rw > 1023) rw = 1023;                          \
    RS = Sp[rs * 32 + k];                                                       \
    RW = Wp[rw * 32 + k];                                                       \
}

// consumer: one row of the serial recurrence.
#define CBODY(d, RW, RS, RT) {                                                  \
    const int i = base + d;                                                     \
    unsigned int W = RW, SC = RS, T = RT;                                       \
    { int pr = i + 4; if (pr > 1024) pr = 1024; int sl = pr & 127;              \
      RW = lW[sl][k]; RS = lS[sl][k]; RT = lT[sl][k]; }                         \
    unsigned int hxp = (prevU << 1) | prevU | ((prevU >> 1) | crp);             \
    unsigned int seed = hxp | T;                                                \
    unsigned int P = W;                                                         \
    unsigned int G = SC | (P & seed);                                           \
    unsigned int A = G | P;                                                     \
    unsigned int AXG = A ^ G;                                                   \
    unsigned int s1v = A + G;                                                   \
    unsigned long long gm = __ballot(s1v < A) & 0xFFFFFFFFull;                  \
    unsigned long long pm = __ballot(s1v == 0xFFFFFFFFu) & 0xFFFFFFFFull;       \
    unsigned long long G0 = __ballot((G & 1u) != 0u);                           \
    unsigned long long P0 = __ballot((P & 1u) != 0u);                           \
    unsigned long long aa = gm | pm;                                            \
    unsigned long long ssum = aa + gm;                                          \
    unsigned long long cvw = ssum ^ aa ^ gm;                                    \
    unsigned long long mlo_o = G0 | (P0 & cvw);                                 \
    unsigned int cin = (((unsigned int)cvw) >> k) & 1u;                         \
    unsigned int ovb = ((((unsigned int)(cvw >> 1)) >> k) & 1u) << 31;          \
    unsigned int s2 = s1v + cin;                                                \
    unsigned int outv = ((s2 ^ AXG) >> 1) | ovb;                                \
    unsigned int rtP = ((((unsigned int)(mlo_o >> 1)) >> k) & 1u) << 31;        \
    crp = cin | rtP;                                                            \
    prevU = outv;                                                               \
    if (i <= 1022) Sp[i * 32 + k] = outv;                                       \
}

__global__ __launch_bounds__(128, 1) __attribute__((amdgpu_waves_per_eu(1, 1)))
void k_track(unsigned int* __restrict__ Sp,
             const unsigned int* __restrict__ Wp) {
    __shared__ unsigned int lW[128][32];   // 16 KB
    __shared__ unsigned int lS[128][32];   // 16 KB
    __shared__ unsigned int lT[128][32];   // 16 KB
    __shared__ unsigned int prodRow, consRow;

    const int tid = threadIdx.x;
    const int k = tid & 31;

    if (tid == 0) { prodRow = 0u; consRow = 0u; }
    __syncthreads();

    if (tid >= 64) {
        // ---------------- producer wave ----------------
        unsigned int SA = Sp[1 * 32 + k];                 // S row 1
        unsigned long long mloA = __ballot((SA & 1u) != 0u);
        unsigned int c0, c1, c2, c3, c4, c5, c6, c7;      // S_{i+1} current group
        unsigned int w0, w1, w2, w3, w4, w5, w6, w7;      // W_i    current group
        unsigned int n0, n1, n2, n3, n4, n5, n6, n7;      // next group
        unsigned int m0, m1, m2, m3, m4, m5, m6, m7;

        // preload group 0 (rows 1..8)
        PLOAD(1, 0, c0, w0) PLOAD(1, 1, c1, w1) PLOAD(1, 2, c2, w2)
        PLOAD(1, 3, c3, w3) PLOAD(1, 4, c4, w4) PLOAD(1, 5, c5, w5)
        PLOAD(1, 6, c6, w6) PLOAD(1, 7, c7, w7)

        #pragma unroll 1
        for (int g = 0; g < 128; ++g) {
            const int gbase = 1 + g * 8;
            // issue next group's loads (used next iteration -> latency hidden)
            if (g < 127) {
                const int nb = gbase + 8;
                PLOAD(nb, 0, n0, m0) PLOAD(nb, 1, n1, m1) PLOAD(nb, 2, n2, m2)
                PLOAD(nb, 3, n3, m3) PLOAD(nb, 4, n4, m4) PLOAD(nb, 5, n5, m5)
                PLOAD(nb, 6, n6, m6) PLOAD(nb, 7, n7, m7)
            }
            // ring backpressure: row gbase+7 reuses slot of row gbase+7-128
            {
                unsigned int target = (unsigned int)(gbase + 8);
                while (target > *((volatile unsigned int*)&consRow) + 104u) { }
                asm volatile("" ::: "memory");
            }
            PBODY(0, c0, w0) PBODY(1, c1, w1) PBODY(2, c2, w2) PBODY(3, c3, w3)
            PBODY(4, c4, w4) PBODY(5, c5, w5) PBODY(6, c6, w6) PBODY(7, c7, w7)
            // publish progress: order data ds_writes before the flag write.
            asm volatile("s_waitcnt lgkmcnt(0)" ::: "memory");
            if (tid == 64) *((volatile unsigned int*)&prodRow) = (unsigned int)(gbase + 8);
            c0 = n0; c1 = n1; c2 = n2; c3 = n3; c4 = n4; c5 = n5; c6 = n6; c7 = n7;
            w0 = m0; w1 = m1; w2 = m2; w3 = m3; w4 = m4; w5 = m5; w6 = m6; w7 = m7;
        }
    } else {
        // ---------------- consumer wave ----------------
        unsigned int pW0, pW1, pW2, pW3, pS0, pS1, pS2, pS3, pT0, pT1, pT2, pT3;
        unsigned int prevU = 0u, crp = 0u;

        // wait for initial margin, then prefetch rows 1..4
        while (*((volatile unsigned int*)&prodRow) < 24u) { }
        asm volatile("" ::: "memory");
        pW0 = lW[1][k]; pS0 = lS[1][k]; pT0 = lT[1][k];
        pW1 = lW[2][k]; pS1 = lS[2][k]; pT1 = lT[2][k];
        pW2 = lW[3][k]; pS2 = lS[3][k]; pT2 = lT[3][k];
        pW3 = lW[4][k]; pS3 = lS[4][k]; pT3 = lT[4][k];

        #pragma unroll 1
        for (int g = 0; g < 64; ++g) {
            const int base = 1 + g * 16;
            if (g > 0) {
                unsigned int target = (unsigned int)(base + 20);
                if (target > 1024u) target = 1024u;
                while (*((volatile unsigned int*)&prodRow) < target) { }
                asm volatile("" ::: "memory");
            }
            CBODY(0,  pW0, pS0, pT0) CBODY(1,  pW1, pS1, pT1)
            CBODY(2,  pW2, pS2, pT2) CBODY(3,  pW3, pS3, pT3)
            CBODY(4,  pW0, pS0, pT0) CBODY(5,  pW1, pS1, pT1)
            CBODY(6,  pW2, pS2, pT2) CBODY(7,  pW3, pS3, pT3)
            CBODY(8,  pW0, pS0, pT0) CBODY(9,  pW1, pS1, pT1)
            CBODY(10, pW2, pS2, pT2) CBODY(11, pW3, pS3, pT3)
            CBODY(12, pW0, pS0, pT0) CBODY(13, pW1, pS1, pT1)
            CBODY(14, pW2, pS2, pT2) CBODY(15, pW3, pS3, pT3)
            if (tid == 0) *((volatile unsigned int*)&consRow) = (unsigned int)(base + 16);
        }
    }
}

// ---------------- Stage 5: unpack bits -> float ----------------
__global__ void k_unpack(const unsigned int* __restrict__ Sp,
                         float* __restrict__ out) {
    int idx = blockIdx.x * blockDim.x + threadIdx.x;
    if (idx >= NPIX) return;
    out[idx] = ((Sp[idx >> 5] >> (idx & 31)) & 1u) ? 1.f : 0.f;
}

extern "C" void kernel_launch(void* const* d_in, const int* in_sizes, int n_in,
                              void* d_out, int out_size, void* d_ws, size_t ws_size,
                              hipStream_t stream) {
    const float* x = (const float*)d_in[0];
    float* out = (float*)d_out;
    char* ws = (char*)d_ws;

    unsigned long long* Sp = (unsigned long long*)(ws);
    unsigned long long* Wp = (unsigned long long*)(ws + 128u * 1024u);

    k_fused<<<1024, 256, 0, stream>>>(x, Sp, Wp);
    k_track<<<1, 128, 0, stream>>>((unsigned int*)Sp, (const unsigned int*)Wp);
    k_unpack<<<4096, 256, 0, stream>>>((const unsigned int*)Sp, out);
}

// Round 9
// 177.359 us; speedup vs baseline: 1.1795x; 1.0228x over previous
//
#include <hip/hip_runtime.h>
#include <math.h>

#define IH 1024
#define IW 1024
#define NPIX (IH * IW)

// ---------------- Stage 1+2+3 fused: gray -> Sobel -> NMS -> bit-packed ----------
__global__ __launch_bounds__(256) void k_fused(const float* __restrict__ x,
                                               unsigned long long* __restrict__ Sp,
                                               unsigned long long* __restrict__ Wp) {
    __shared__ float g[20][72];
    __shared__ float m[18][68];
    const int bx = blockIdx.x & 15, by = blockIdx.x >> 4;
    const int tid = threadIdx.x;
    const int gi0 = by * 16 - 2, gj0 = bx * 64 - 2;

    for (int e = tid; e < 20 * 68; e += 256) {
        int ly = e / 68, lx = e - ly * 68;
        int gy = gi0 + ly, gxc = gj0 + lx;
        float v = 0.f;
        if ((unsigned)gy < (unsigned)IH && (unsigned)gxc < (unsigned)IW) {
            int p = gy * IW + gxc;
            float r = x[p], gg = x[NPIX + p], b = x[2 * NPIX + p];
            v = __fadd_rn(__fadd_rn(__fmul_rn(r, 0.2989f), __fmul_rn(gg, 0.587f)),
                          __fmul_rn(b, 0.114f));
        }
        g[ly][lx] = v;
    }
    __syncthreads();

    for (int e = tid; e < 18 * 66; e += 256) {
        int ly = e / 66, lx = e - ly * 66;
        float a00 = g[ly][lx],   a01 = g[ly][lx+1],   a02 = g[ly][lx+2];
        float a10 = g[ly+1][lx],                      a12 = g[ly+1][lx+2];
        float a20 = g[ly+2][lx], a21 = g[ly+2][lx+1], a22 = g[ly+2][lx+2];
        float gx = __fmul_rn(-1.f, a00);
        gx = __fadd_rn(gx, a02);
        gx = __fadd_rn(gx, __fmul_rn(-2.f, a10));
        gx = __fadd_rn(gx, __fmul_rn(2.f, a12));
        gx = __fadd_rn(gx, __fmul_rn(-1.f, a20));
        gx = __fadd_rn(gx, a22);
        float gy = a00;
        gy = __fadd_rn(gy, __fmul_rn(2.f, a01));
        gy = __fadd_rn(gy, a02);
        gy = __fadd_rn(gy, __fmul_rn(-1.f, a20));
        gy = __fadd_rn(gy, __fmul_rn(-2.f, a21));
        gy = __fadd_rn(gy, __fmul_rn(-1.f, a22));
        m[ly][lx] = __fsqrt_rn(__fadd_rn(__fmul_rn(gx, gx), __fmul_rn(gy, gy)));
    }
    __syncthreads();

    const int lane = tid & 63;
    const int wv = tid >> 6;
    #pragma unroll
    for (int rr = 0; rr < 4; ++rr) {
        int ti = wv * 4 + rr;
        int i = by * 16 + ti, j = bx * 64 + lane;
        float a00 = g[ti+1][lane+1], a01 = g[ti+1][lane+2], a02 = g[ti+1][lane+3];
        float a10 = g[ti+2][lane+1],                         a12 = g[ti+2][lane+3];
        float a20 = g[ti+3][lane+1], a21 = g[ti+3][lane+2], a22 = g[ti+3][lane+3];
        float gx = __fmul_rn(-1.f, a00);
        gx = __fadd_rn(gx, a02);
        gx = __fadd_rn(gx, __fmul_rn(-2.f, a10));
        gx = __fadd_rn(gx, __fmul_rn(2.f, a12));
        gx = __fadd_rn(gx, __fmul_rn(-1.f, a20));
        gx = __fadd_rn(gx, a22);
        float gy = a00;
        gy = __fadd_rn(gy, __fmul_rn(2.f, a01));
        gy = __fadd_rn(gy, a02);
        gy = __fadd_rn(gy, __fmul_rn(-1.f, a20));
        gy = __fadd_rn(gy, __fmul_rn(-2.f, a21));
        gy = __fadd_rn(gy, __fmul_rn(-1.f, a22));

        float ai = __fmul_rn(atan2f(gy, gx), 57.295779513082320876798154814105f);
        float c = m[ti+1][lane+1];
        float n1, n2;
        if (ai < -22.5f || ai >= 157.5f)      { n1 = m[ti+1][lane];   n2 = m[ti+1][lane+2]; }
        else if (ai < 22.5f)                  { n1 = m[ti][lane+1];   n2 = m[ti+2][lane+1]; }
        else if (ai < 67.5f)                  { n1 = m[ti][lane];     n2 = m[ti+2][lane+2]; }
        else if (ai < 112.5f)                 { n1 = m[ti][lane+1];   n2 = m[ti+2][lane+1]; }
        else                                  { n1 = m[ti][lane+2];   n2 = m[ti+2][lane];   }
        bool border = (i == 0) | (i == IH - 1) | (j == 0) | (j == IW - 1);
        bool keep = (c >= n1) && (c >= n2);
        float supp = keep ? c : 0.f;
        bool sb = !border && (supp >= 50.f);
        bool wb = !border && (supp >= 20.f) && !(supp >= 50.f);
        unsigned long long bs = __ballot(sb);
        unsigned long long bw = __ballot(wb);
        if (lane == 0) {
            Sp[i * 16 + bx] = bs;
            Wp[i * 16 + bx] = bw;
        }
    }
}

// ---------------- Stage 3.5: STAT = Rx(S_i) | Hx(S_{i+1}), fully parallel ------
__global__ void k_prep2(const unsigned int* __restrict__ Sp,
                        unsigned int* __restrict__ St) {
    int idx = blockIdx.x * blockDim.x + threadIdx.x;   // 0 .. 32767
    int r = idx >> 5, w = idx & 31;
    int rn = r + 1; if (rn > 1023) rn = 1023;
    unsigned int S  = Sp[r * 32 + w];
    unsigned int Sr = (w < 31) ? Sp[r * 32 + w + 1] : 0u;
    unsigned int N  = Sp[rn * 32 + w];
    unsigned int Nl = (w > 0)  ? Sp[rn * 32 + w - 1] : 0u;
    unsigned int Nr = (w < 31) ? Sp[rn * 32 + w + 1] : 0u;
    unsigned int Rx = S | (S >> 1) | ((Sr & 1u) << 31);
    unsigned int Hx = N | (N << 1) | (N >> 1) | ((Nl >> 31) & 1u) | ((Nr & 1u) << 31);
    St[idx] = Rx | Hx;
}

// async global->LDS DMA: 64 lanes x 4B = 256 B = 2 ring rows per instruction
__device__ __forceinline__ void dma4(const unsigned int* g, unsigned int* l) {
    __builtin_amdgcn_global_load_lds(
        (const __attribute__((address_space(1))) void*)g,
        (__attribute__((address_space(3))) void*)l, 4, 0, 0);
}

// ---------------- Stage 4: DMA-producer / compute-consumer tracker ----------------
// consumer: one row of the serial recurrence (math identical to R8, absmax 0).
#define CBODY(d, n) {                                                           \
    const int i = base + d;                                                     \
    unsigned int W = pW##n, SC = pS##n, T = pT##n;                              \
    { int pr = i + 8; if (pr > 1023) pr = 1023; int sl = pr & 127;              \
      pW##n = ringW[sl * 32 + k];                                               \
      pS##n = ringS[sl * 32 + k];                                               \
      pT##n = ringT[sl * 32 + k]; }                                             \
    unsigned int hxp = (prevU << 1) | prevU | ((prevU >> 1) | crp);             \
    unsigned int seed = hxp | T;                                                \
    unsigned int P = W;                                                         \
    unsigned int G = SC | (P & seed);                                           \
    unsigned int A = G | P;                                                     \
    unsigned int AXG = A ^ G;                                                   \
    unsigned int s1v = A + G;                                                   \
    unsigned long long gm = __ballot(s1v < A) & 0xFFFFFFFFull;                  \
    unsigned long long pm = __ballot(s1v == 0xFFFFFFFFu) & 0xFFFFFFFFull;       \
    unsigned long long G0 = __ballot((G & 1u) != 0u);                           \
    unsigned long long P0 = __ballot((P & 1u) != 0u);                           \
    unsigned long long aa = gm | pm;                                            \
    unsigned long long ssum = aa + gm;                                          \
    unsigned long long cvw = ssum ^ aa ^ gm;                                    \
    unsigned long long mlo_o = G0 | (P0 & cvw);                                 \
    unsigned int cin = (((unsigned int)cvw) >> k) & 1u;                         \
    unsigned int ovb = ((((unsigned int)(cvw >> 1)) >> k) & 1u) << 31;          \
    unsigned int s2 = s1v + cin;                                                \
    unsigned int outv = ((s2 ^ AXG) >> 1) | ovb;                                \
    unsigned int rtP = ((((unsigned int)(mlo_o >> 1)) >> k) & 1u) << 31;        \
    crp = cin | rtP;                                                            \
    prevU = outv;                                                               \
    if (i <= 1022) Sp[i * 32 + k] = outv;                                       \
}

__global__ __launch_bounds__(128, 1) __attribute__((amdgpu_waves_per_eu(1, 1)))
void k_track(unsigned int* __restrict__ Sp,
             const unsigned int* __restrict__ Wp,
             const unsigned int* __restrict__ St) {
    __shared__ unsigned int ringW[128 * 32];   // 16 KB each
    __shared__ unsigned int ringS[128 * 32];
    __shared__ unsigned int ringT[128 * 32];
    __shared__ unsigned int prodRow, consRow;

    const int tid = threadIdx.x;
    const int k = tid & 31;

    if (tid == 0) { prodRow = 0u; consRow = 0u; }
    __syncthreads();

    if (tid >= 64) {
        // ---------------- producer wave: pure DMA streamer ----------------
        const int lane = tid & 63;
        #pragma unroll 1
        for (int g = 0; g < 128; ++g) {
            // ring backpressure: group g writes rows 8g..8g+7 over rows 8g-128..
            while ((unsigned)(8 * g) > *((volatile unsigned int*)&consRow) + 120u) { }
            asm volatile("" ::: "memory");
            #pragma unroll
            for (int j = 0; j < 4; ++j) {
                int row = g * 8 + 2 * j;
                int sl = row & 127;
                dma4(Wp + row * 32 + lane, &ringW[sl * 32]);
                dma4(Sp + row * 32 + lane, &ringS[sl * 32]);
                dma4(St + row * 32 + lane, &ringT[sl * 32]);
            }
            // keep <=2 groups in flight; group g-2 now complete -> publish
            asm volatile("s_waitcnt vmcnt(24)" ::: "memory");
            if (tid == 64 && g >= 2)
                *((volatile unsigned int*)&prodRow) = (unsigned int)(8 * g - 8);
        }
        asm volatile("s_waitcnt vmcnt(0)" ::: "memory");
        if (tid == 64) *((volatile unsigned int*)&prodRow) = 1024u;
    } else {
        // ---------------- consumer wave: serial recurrence ----------------
        unsigned int pW0, pW1, pW2, pW3, pW4, pW5, pW6, pW7;
        unsigned int pS0, pS1, pS2, pS3, pS4, pS5, pS6, pS7;
        unsigned int pT0, pT1, pT2, pT3, pT4, pT5, pT6, pT7;
        unsigned int prevU = 0u, crp = 0u;

        while (*((volatile unsigned int*)&prodRow) < 32u) { }
        asm volatile("" ::: "memory");
        pW0 = ringW[1*32+k]; pS0 = ringS[1*32+k]; pT0 = ringT[1*32+k];
        pW1 = ringW[2*32+k]; pS1 = ringS[2*32+k]; pT1 = ringT[2*32+k];
        pW2 = ringW[3*32+k]; pS2 = ringS[3*32+k]; pT2 = ringT[3*32+k];
        pW3 = ringW[4*32+k]; pS3 = ringS[4*32+k]; pT3 = ringT[4*32+k];
        pW4 = ringW[5*32+k]; pS4 = ringS[5*32+k]; pT4 = ringT[5*32+k];
        pW5 = ringW[6*32+k]; pS5 = ringS[6*32+k]; pT5 = ringT[6*32+k];
        pW6 = ringW[7*32+k]; pS6 = ringS[7*32+k]; pT6 = ringT[7*32+k];
        pW7 = ringW[8*32+k]; pS7 = ringS[8*32+k]; pT7 = ringT[8*32+k];

        #pragma unroll 1
        for (int g = 0; g < 64; ++g) {
            const int base = 1 + g * 16;
            {
                unsigned int target = (unsigned int)(base + 24);
                if (target > 1024u) target = 1024u;
                while (*((volatile unsigned int*)&prodRow) < target) { }
                asm volatile("" ::: "memory");
            }
            CBODY(0, 0) CBODY(1, 1) CBODY(2, 2) CBODY(3, 3)
            CBODY(4, 4) CBODY(5, 5) CBODY(6, 6) CBODY(7, 7)
            CBODY(8, 0) CBODY(9, 1) CBODY(10, 2) CBODY(11, 3)
            CBODY(12, 4) CBODY(13, 5) CBODY(14, 6) CBODY(15, 7)
            if (tid == 0) *((volatile unsigned int*)&consRow) = (unsigned int)(base + 16);
        }
    }
}

// ---------------- Stage 5: unpack bits -> float ----------------
__global__ void k_unpack(const unsigned int* __restrict__ Sp,
                         float* __restrict__ out) {
    int idx = blockIdx.x * blockDim.x + threadIdx.x;
    if (idx >= NPIX) return;
    out[idx] = ((Sp[idx >> 5] >> (idx & 31)) & 1u) ? 1.f : 0.f;
}

extern "C" void kernel_launch(void* const* d_in, const int* in_sizes, int n_in,
                              void* d_out, int out_size, void* d_ws, size_t ws_size,
                              hipStream_t stream) {
    const float* x = (const float*)d_in[0];
    float* out = (float*)d_out;
    char* ws = (char*)d_ws;

    unsigned long long* Sp = (unsigned long long*)(ws);
    unsigned long long* Wp = (unsigned long long*)(ws + 128u * 1024u);
    unsigned int*       St = (unsigned int*)(ws + 256u * 1024u);

    k_fused<<<1024, 256, 0, stream>>>(x, Sp, Wp);
    k_prep2<<<128, 256, 0, stream>>>((const unsigned int*)Sp, St);
    k_track<<<1, 128, 0, stream>>>((unsigned int*)Sp, (const unsigned int*)Wp,
                                   (const unsigned int*)St);
    k_unpack<<<4096, 256, 0, stream>>>((const unsigned int*)Sp, out);
}

// Round 10
// 104.693 us; speedup vs baseline: 1.9982x; 1.6941x over previous
//
#include <hip/hip_runtime.h>
#include <math.h>

#define IH 1024
#define IW 1024
#define NPIX (IH * IW)
#define NW 16   // chunks = waves
#define CH 64   // rows per chunk

// ---------------- Stage 1+2+3 fused: gray -> Sobel -> NMS -> bit-packed ----------
__global__ __launch_bounds__(256) void k_fused(const float* __restrict__ x,
                                               unsigned long long* __restrict__ Sp,
                                               unsigned long long* __restrict__ Wp) {
    __shared__ float g[20][72];
    __shared__ float m[18][68];
    const int bx = blockIdx.x & 15, by = blockIdx.x >> 4;
    const int tid = threadIdx.x;
    const int gi0 = by * 16 - 2, gj0 = bx * 64 - 2;

    for (int e = tid; e < 20 * 68; e += 256) {
        int ly = e / 68, lx = e - ly * 68;
        int gy = gi0 + ly, gxc = gj0 + lx;
        float v = 0.f;
        if ((unsigned)gy < (unsigned)IH && (unsigned)gxc < (unsigned)IW) {
            int p = gy * IW + gxc;
            float r = x[p], gg = x[NPIX + p], b = x[2 * NPIX + p];
            v = __fadd_rn(__fadd_rn(__fmul_rn(r, 0.2989f), __fmul_rn(gg, 0.587f)),
                          __fmul_rn(b, 0.114f));
        }
        g[ly][lx] = v;
    }
    __syncthreads();

    for (int e = tid; e < 18 * 66; e += 256) {
        int ly = e / 66, lx = e - ly * 66;
        float a00 = g[ly][lx],   a01 = g[ly][lx+1],   a02 = g[ly][lx+2];
        float a10 = g[ly+1][lx],                      a12 = g[ly+1][lx+2];
        float a20 = g[ly+2][lx], a21 = g[ly+2][lx+1], a22 = g[ly+2][lx+2];
        float gx = __fmul_rn(-1.f, a00);
        gx = __fadd_rn(gx, a02);
        gx = __fadd_rn(gx, __fmul_rn(-2.f, a10));
        gx = __fadd_rn(gx, __fmul_rn(2.f, a12));
        gx = __fadd_rn(gx, __fmul_rn(-1.f, a20));
        gx = __fadd_rn(gx, a22);
        float gy = a00;
        gy = __fadd_rn(gy, __fmul_rn(2.f, a01));
        gy = __fadd_rn(gy, a02);
        gy = __fadd_rn(gy, __fmul_rn(-1.f, a20));
        gy = __fadd_rn(gy, __fmul_rn(-2.f, a21));
        gy = __fadd_rn(gy, __fmul_rn(-1.f, a22));
        m[ly][lx] = __fsqrt_rn(__fadd_rn(__fmul_rn(gx, gx), __fmul_rn(gy, gy)));
    }
    __syncthreads();

    const int lane = tid & 63;
    const int wv = tid >> 6;
    #pragma unroll
    for (int rr = 0; rr < 4; ++rr) {
        int ti = wv * 4 + rr;
        int i = by * 16 + ti, j = bx * 64 + lane;
        float a00 = g[ti+1][lane+1], a01 = g[ti+1][lane+2], a02 = g[ti+1][lane+3];
        float a10 = g[ti+2][lane+1],                         a12 = g[ti+2][lane+3];
        float a20 = g[ti+3][lane+1], a21 = g[ti+3][lane+2], a22 = g[ti+3][lane+3];
        float gx = __fmul_rn(-1.f, a00);
        gx = __fadd_rn(gx, a02);
        gx = __fadd_rn(gx, __fmul_rn(-2.f, a10));
        gx = __fadd_rn(gx, __fmul_rn(2.f, a12));
        gx = __fadd_rn(gx, __fmul_rn(-1.f, a20));
        gx = __fadd_rn(gx, a22);
        float gy = a00;
        gy = __fadd_rn(gy, __fmul_rn(2.f, a01));
        gy = __fadd_rn(gy, a02);
        gy = __fadd_rn(gy, __fmul_rn(-1.f, a20));
        gy = __fadd_rn(gy, __fmul_rn(-2.f, a21));
        gy = __fadd_rn(gy, __fmul_rn(-1.f, a22));

        float ai = __fmul_rn(atan2f(gy, gx), 57.295779513082320876798154814105f);
        float c = m[ti+1][lane+1];
        float n1, n2;
        if (ai < -22.5f || ai >= 157.5f)      { n1 = m[ti+1][lane];   n2 = m[ti+1][lane+2]; }
        else if (ai < 22.5f)                  { n1 = m[ti][lane+1];   n2 = m[ti+2][lane+1]; }
        else if (ai < 67.5f)                  { n1 = m[ti][lane];     n2 = m[ti+2][lane+2]; }
        else if (ai < 112.5f)                 { n1 = m[ti][lane+1];   n2 = m[ti+2][lane+1]; }
        else                                  { n1 = m[ti][lane+2];   n2 = m[ti+2][lane];   }
        bool border = (i == 0) | (i == IH - 1) | (j == 0) | (j == IW - 1);
        bool keep = (c >= n1) && (c >= n2);
        float supp = keep ? c : 0.f;
        bool sb = !border && (supp >= 50.f);
        bool wb = !border && (supp >= 20.f) && !(supp >= 50.f);
        unsigned long long bs = __ballot(sb);
        unsigned long long bw = __ballot(wb);
        if (lane == 0) {
            Sp[i * 16 + bx] = bs;
            Wp[i * 16 + bx] = bw;
        }
    }
}

// ---------------- Stage 3.5: STAT = Rx(S_i) | Hx(S_{i+1}), fully parallel ------
__global__ void k_prep2(const unsigned int* __restrict__ Sp,
                        unsigned int* __restrict__ St) {
    int idx = blockIdx.x * blockDim.x + threadIdx.x;   // 0 .. 32767
    int r = idx >> 5, w = idx & 31;
    int rn = r + 1; if (rn > 1023) rn = 1023;
    unsigned int S  = Sp[r * 32 + w];
    unsigned int Sr = (w < 31) ? Sp[r * 32 + w + 1] : 0u;
    unsigned int N  = Sp[rn * 32 + w];
    unsigned int Nl = (w > 0)  ? Sp[rn * 32 + w - 1] : 0u;
    unsigned int Nr = (w < 31) ? Sp[rn * 32 + w + 1] : 0u;
    unsigned int Rx = S | (S >> 1) | ((Sr & 1u) << 31);
    unsigned int Hx = N | (N << 1) | (N >> 1) | ((Nl >> 31) & 1u) | ((Nr & 1u) << 31);
    St[idx] = Rx | Hx;
}

__device__ __forceinline__ void dma4(const unsigned int* g, unsigned int* l) {
    __builtin_amdgcn_global_load_lds(
        (const __attribute__((address_space(1))) void*)g,
        (__attribute__((address_space(3))) void*)l, 4, 0, 0);
}

// One row of the recurrence: out = G | P&(out<<1col), adder-carry formulation
// (math identical to R8/R9, absmax 0).  Uses/updates prevU, crp from scope.
#define CHAIN_STEP(W_, S_, T_)                                                  \
    unsigned int hxp = (prevU << 1) | prevU | ((prevU >> 1) | crp);             \
    unsigned int seed = hxp | (T_);                                             \
    unsigned int P = (W_);                                                      \
    unsigned int G = (S_) | (P & seed);                                         \
    unsigned int A = G | P;                                                     \
    unsigned int AXG = A ^ G;                                                   \
    unsigned int s1v = A + G;                                                   \
    unsigned long long gm = __ballot(s1v < A) & 0xFFFFFFFFull;                  \
    unsigned long long pm = __ballot(s1v == 0xFFFFFFFFu) & 0xFFFFFFFFull;       \
    unsigned long long G0 = __ballot((G & 1u) != 0u);                           \
    unsigned long long P0 = __ballot((P & 1u) != 0u);                           \
    unsigned long long aa = gm | pm;                                            \
    unsigned long long ssum = aa + gm;                                          \
    unsigned long long cvw = ssum ^ aa ^ gm;                                    \
    unsigned long long mlo_o = G0 | (P0 & cvw);                                 \
    unsigned int cin = (((unsigned int)cvw) >> k) & 1u;                         \
    unsigned int ovb = ((((unsigned int)(cvw >> 1)) >> k) & 1u) << 31;          \
    unsigned int s2 = s1v + cin;                                                \
    unsigned int outv = ((s2 ^ AXG) >> 1) | ovb;                                \
    unsigned int rtP = ((((unsigned int)(mlo_o >> 1)) >> k) & 1u) << 31;        \
    crp = cin | rtP;                                                            \
    prevU = outv;

// ---------------- Stage 4: speculative-chunk tracker ----------------
// 16 waves = 16 chunks of 64 rows.  Phase 1: each chunk solves with
// prev = S_static (lower bound) in parallel, writing spec to Osp.
// Phase 2: sequential fixup; chunk c recomputes with true boundary until
// recomputed row == spec row (then the suffix is provably identical).
__global__ __launch_bounds__(1024, 1)
void k_track(const unsigned int* __restrict__ Sp,
             const unsigned int* __restrict__ Wp,
             const unsigned int* __restrict__ St,
             unsigned int* __restrict__ Osp) {
    __shared__ unsigned int ringW[NW][8][32];
    __shared__ unsigned int ringS[NW][8][32];
    __shared__ unsigned int ringT[NW][8][32];
    __shared__ unsigned int arrO[NW][6][32];
    __shared__ unsigned int prevRowLds[NW][32];
    __shared__ unsigned int fixedUpTo;

    const int tid = threadIdx.x;
    const int c = tid >> 6;
    const int lane = tid & 63;
    const int k = lane & 31;
    const int r0 = c * CH + 1;

    if (tid == 0) fixedUpTo = 0u;
    if (c == 0 && lane < 32) Osp[k] = 0u;            // out row 0 = 0
    if (c == NW - 1 && lane < 32) Osp[1023 * 32 + k] = 0u;  // out row 1023 = 0

    // ---- phase 1: speculative solve ----
    for (int g = 0; g < 3; ++g) {
        int row = r0 + 2 * g;
        dma4(Wp + row * 32 + lane, &ringW[c][(2 * g) & 7][0]);
        dma4(Sp + row * 32 + lane, &ringS[c][(2 * g) & 7][0]);
        dma4(St + row * 32 + lane, &ringT[c][(2 * g) & 7][0]);
    }
    unsigned int prevU = Sp[(r0 - 1) * 32 + k];      // static lower bound
    unsigned int crp;
    {
        unsigned long long mh = __ballot((prevU >> 31) != 0u);
        unsigned long long ml = __ballot((prevU & 1u) != 0u);
        crp = ((((unsigned int)(mh << 1)) >> k) & 1u)
            | (((((unsigned int)(ml >> 1)) >> k) & 1u) << 31);
    }
    #pragma unroll 1
    for (int t = 0; t < 32; ++t) {
        if (t < 29) {
            int row = r0 + 2 * (t + 3);
            dma4(Wp + row * 32 + lane, &ringW[c][(2 * t + 6) & 7][0]);
            dma4(Sp + row * 32 + lane, &ringS[c][(2 * t + 6) & 7][0]);
            dma4(St + row * 32 + lane, &ringT[c][(2 * t + 6) & 7][0]);
        }
        asm volatile("s_waitcnt vmcnt(9)" ::: "memory");
        #pragma unroll
        for (int j = 0; j < 2; ++j) {
            int r = r0 + 2 * t + j;
            int sl = (2 * t + j) & 7;
            unsigned int Wv = ringW[c][sl][k];
            unsigned int Sv = ringS[c][sl][k];
            unsigned int Tv = ringT[c][sl][k];
            {
                CHAIN_STEP(Wv, Sv, Tv)
                if (r <= 1022) Osp[r * 32 + k] = outv;
            }
        }
    }

    __syncthreads();   // spec complete + visible (barrier drains vm/lgkm)

    // ---- phase 2 prestage: statics rows r0..r0+7, spec rows r0..r0+5 ----
    for (int g = 0; g < 4; ++g) {
        int row = r0 + 2 * g;
        dma4(Wp + row * 32 + lane, &ringW[c][2 * g][0]);
        dma4(Sp + row * 32 + lane, &ringS[c][2 * g][0]);
        dma4(St + row * 32 + lane, &ringT[c][2 * g][0]);
    }
    dma4(Osp + r0 * 32 + lane,       &arrO[c][0][0]);
    dma4(Osp + (r0 + 2) * 32 + lane, &arrO[c][2][0]);
    dma4(Osp + (r0 + 4) * 32 + lane, &arrO[c][4][0]);
    asm volatile("s_waitcnt vmcnt(0)" ::: "memory");

    if (c > 0) {
        while (*((volatile unsigned int*)&fixedUpTo) != (unsigned int)c) {
            __builtin_amdgcn_s_sleep(2);
        }
        asm volatile("" ::: "memory");
        prevU = prevRowLds[c][k];                    // true last row of chunk c-1
        {
            unsigned long long mh = __ballot((prevU >> 31) != 0u);
            unsigned long long ml = __ballot((prevU & 1u) != 0u);
            crp = ((((unsigned int)(mh << 1)) >> k) & 1u)
                | (((((unsigned int)(ml >> 1)) >> k) & 1u) << 31);
        }
        #pragma unroll 1
        for (int d = 0; d < CH; ++d) {
            int r = r0 + d;
            if (r > 1022) break;
            unsigned int Wv, Sv, Tv, spec;
            if (d < 8) { Wv = ringW[c][d][k]; Sv = ringS[c][d][k]; Tv = ringT[c][d][k]; }
            else       { Wv = Wp[r * 32 + k]; Sv = Sp[r * 32 + k]; Tv = St[r * 32 + k]; }
            spec = (d < 6) ? arrO[c][d][k] : Osp[r * 32 + k];
            bool conv;
            {
                CHAIN_STEP(Wv, Sv, Tv)
                unsigned long long df = __ballot(outv != spec);
                conv = ((df & 0xFFFFFFFFull) == 0ull);
                if (!conv) Osp[r * 32 + k] = outv;
            }
            if (conv) break;                         // suffix provably identical
        }
        asm volatile("s_waitcnt vmcnt(0)" ::: "memory");
    }
    // deposit true boundary row for the next chunk, then publish turn
    if (c < NW - 1) {
        unsigned int v = Osp[(r0 + CH - 1) * 32 + k];   // row 64*(c+1), now true
        prevRowLds[c + 1][k] = v;
    }
    asm volatile("s_waitcnt lgkmcnt(0)" ::: "memory");
    if (lane == 0) *((volatile unsigned int*)&fixedUpTo) = (unsigned int)(c + 1);
}

// ---------------- Stage 5: unpack bits -> float ----------------
__global__ void k_unpack(const unsigned int* __restrict__ Osp,
                         float* __restrict__ out) {
    int idx = blockIdx.x * blockDim.x + threadIdx.x;
    if (idx >= NPIX) return;
    out[idx] = ((Osp[idx >> 5] >> (idx & 31)) & 1u) ? 1.f : 0.f;
}

extern "C" void kernel_launch(void* const* d_in, const int* in_sizes, int n_in,
                              void* d_out, int out_size, void* d_ws, size_t ws_size,
                              hipStream_t stream) {
    const float* x = (const float*)d_in[0];
    float* out = (float*)d_out;
    char* ws = (char*)d_ws;

    unsigned long long* Sp = (unsigned long long*)(ws);
    unsigned long long* Wp = (unsigned long long*)(ws + 128u * 1024u);
    unsigned int*       St = (unsigned int*)(ws + 256u * 1024u);
    unsigned int*      Osp = (unsigned int*)(ws + 384u * 1024u);

    k_fused<<<1024, 256, 0, stream>>>(x, Sp, Wp);
    k_prep2<<<128, 256, 0, stream>>>((const unsigned int*)Sp, St);
    k_track<<<1, 1024, 0, stream>>>((const unsigned int*)Sp, (const unsigned int*)Wp,
                                    (const unsigned int*)St, Osp);
    k_unpack<<<4096, 256, 0, stream>>>((const unsigned int*)Osp, out);
}

// Round 11
// 103.037 us; speedup vs baseline: 2.0304x; 1.0161x over previous
//
#include <hip/hip_runtime.h>
#include <math.h>

#define IH 1024
#define IW 1024
#define NPIX (IH * IW)
#define NW 16   // chunks = waves
#define CH 64   // rows per chunk

// ---------------- Stage 1+2+3 fused: gray -> Sobel -> NMS -> bit-packed ----------
__global__ __launch_bounds__(256) void k_fused(const float* __restrict__ x,
                                               unsigned long long* __restrict__ Sp,
                                               unsigned long long* __restrict__ Wp) {
    __shared__ float g[20][72];
    __shared__ float m[18][68];
    const int bx = blockIdx.x & 15, by = blockIdx.x >> 4;
    const int tid = threadIdx.x;
    const int gi0 = by * 16 - 2, gj0 = bx * 64 - 2;

    for (int e = tid; e < 20 * 68; e += 256) {
        int ly = e / 68, lx = e - ly * 68;
        int gy = gi0 + ly, gxc = gj0 + lx;
        float v = 0.f;
        if ((unsigned)gy < (unsigned)IH && (unsigned)gxc < (unsigned)IW) {
            int p = gy * IW + gxc;
            float r = x[p], gg = x[NPIX + p], b = x[2 * NPIX + p];
            v = __fadd_rn(__fadd_rn(__fmul_rn(r, 0.2989f), __fmul_rn(gg, 0.587f)),
                          __fmul_rn(b, 0.114f));
        }
        g[ly][lx] = v;
    }
    __syncthreads();

    for (int e = tid; e < 18 * 66; e += 256) {
        int ly = e / 66, lx = e - ly * 66;
        float a00 = g[ly][lx],   a01 = g[ly][lx+1],   a02 = g[ly][lx+2];
        float a10 = g[ly+1][lx],                      a12 = g[ly+1][lx+2];
        float a20 = g[ly+2][lx], a21 = g[ly+2][lx+1], a22 = g[ly+2][lx+2];
        float gx = __fmul_rn(-1.f, a00);
        gx = __fadd_rn(gx, a02);
        gx = __fadd_rn(gx, __fmul_rn(-2.f, a10));
        gx = __fadd_rn(gx, __fmul_rn(2.f, a12));
        gx = __fadd_rn(gx, __fmul_rn(-1.f, a20));
        gx = __fadd_rn(gx, a22);
        float gy = a00;
        gy = __fadd_rn(gy, __fmul_rn(2.f, a01));
        gy = __fadd_rn(gy, a02);
        gy = __fadd_rn(gy, __fmul_rn(-1.f, a20));
        gy = __fadd_rn(gy, __fmul_rn(-2.f, a21));
        gy = __fadd_rn(gy, __fmul_rn(-1.f, a22));
        m[ly][lx] = __fsqrt_rn(__fadd_rn(__fmul_rn(gx, gx), __fmul_rn(gy, gy)));
    }
    __syncthreads();

    const int lane = tid & 63;
    const int wv = tid >> 6;
    #pragma unroll
    for (int rr = 0; rr < 4; ++rr) {
        int ti = wv * 4 + rr;
        int i = by * 16 + ti, j = bx * 64 + lane;
        float a00 = g[ti+1][lane+1], a01 = g[ti+1][lane+2], a02 = g[ti+1][lane+3];
        float a10 = g[ti+2][lane+1],                         a12 = g[ti+2][lane+3];
        float a20 = g[ti+3][lane+1], a21 = g[ti+3][lane+2], a22 = g[ti+3][lane+3];
        float gx = __fmul_rn(-1.f, a00);
        gx = __fadd_rn(gx, a02);
        gx = __fadd_rn(gx, __fmul_rn(-2.f, a10));
        gx = __fadd_rn(gx, __fmul_rn(2.f, a12));
        gx = __fadd_rn(gx, __fmul_rn(-1.f, a20));
        gx = __fadd_rn(gx, a22);
        float gy = a00;
        gy = __fadd_rn(gy, __fmul_rn(2.f, a01));
        gy = __fadd_rn(gy, a02);
        gy = __fadd_rn(gy, __fmul_rn(-1.f, a20));
        gy = __fadd_rn(gy, __fmul_rn(-2.f, a21));
        gy = __fadd_rn(gy, __fmul_rn(-1.f, a22));

        float ai = __fmul_rn(atan2f(gy, gx), 57.295779513082320876798154814105f);
        float c = m[ti+1][lane+1];
        float n1, n2;
        if (ai < -22.5f || ai >= 157.5f)      { n1 = m[ti+1][lane];   n2 = m[ti+1][lane+2]; }
        else if (ai < 22.5f)                  { n1 = m[ti][lane+1];   n2 = m[ti+2][lane+1]; }
        else if (ai < 67.5f)                  { n1 = m[ti][lane];     n2 = m[ti+2][lane+2]; }
        else if (ai < 112.5f)                 { n1 = m[ti][lane+1];   n2 = m[ti+2][lane+1]; }
        else                                  { n1 = m[ti][lane+2];   n2 = m[ti+2][lane];   }
        bool border = (i == 0) | (i == IH - 1) | (j == 0) | (j == IW - 1);
        bool keep = (c >= n1) && (c >= n2);
        float supp = keep ? c : 0.f;
        bool sb = !border && (supp >= 50.f);
        bool wb = !border && (supp >= 20.f) && !(supp >= 50.f);
        unsigned long long bs = __ballot(sb);
        unsigned long long bw = __ballot(wb);
        if (lane == 0) {
            Sp[i * 16 + bx] = bs;
            Wp[i * 16 + bx] = bw;
        }
    }
}

// ---------------- Stage 3.5: STAT = Rx(S_i) | Hx(S_{i+1}), fully parallel ------
__global__ void k_prep2(const unsigned int* __restrict__ Sp,
                        unsigned int* __restrict__ St) {
    int idx = blockIdx.x * blockDim.x + threadIdx.x;   // 0 .. 32767
    int r = idx >> 5, w = idx & 31;
    int rn = r + 1; if (rn > 1023) rn = 1023;
    unsigned int S  = Sp[r * 32 + w];
    unsigned int Sr = (w < 31) ? Sp[r * 32 + w + 1] : 0u;
    unsigned int N  = Sp[rn * 32 + w];
    unsigned int Nl = (w > 0)  ? Sp[rn * 32 + w - 1] : 0u;
    unsigned int Nr = (w < 31) ? Sp[rn * 32 + w + 1] : 0u;
    unsigned int Rx = S | (S >> 1) | ((Sr & 1u) << 31);
    unsigned int Hx = N | (N << 1) | (N >> 1) | ((Nl >> 31) & 1u) | ((Nr & 1u) << 31);
    St[idx] = Rx | Hx;
}

__device__ __forceinline__ void dma4(const unsigned int* g, unsigned int* l) {
    __builtin_amdgcn_global_load_lds(
        (const __attribute__((address_space(1))) void*)g,
        (__attribute__((address_space(3))) void*)l, 4, 0, 0);
}

// One row of the recurrence (math identical to R8-R10, absmax 0).
#define CHAIN_STEP(W_, S_, T_)                                                  \
    unsigned int hxp = (prevU << 1) | prevU | ((prevU >> 1) | crp);             \
    unsigned int seed = hxp | (T_);                                             \
    unsigned int P = (W_);                                                      \
    unsigned int G = (S_) | (P & seed);                                         \
    unsigned int A = G | P;                                                     \
    unsigned int AXG = A ^ G;                                                   \
    unsigned int s1v = A + G;                                                   \
    unsigned long long gm = __ballot(s1v < A) & 0xFFFFFFFFull;                  \
    unsigned long long pm = __ballot(s1v == 0xFFFFFFFFu) & 0xFFFFFFFFull;       \
    unsigned long long G0 = __ballot((G & 1u) != 0u);                           \
    unsigned long long P0 = __ballot((P & 1u) != 0u);                           \
    unsigned long long aa = gm | pm;                                            \
    unsigned long long ssum = aa + gm;                                          \
    unsigned long long cvw = ssum ^ aa ^ gm;                                    \
    unsigned long long mlo_o = G0 | (P0 & cvw);                                 \
    unsigned int cin = (((unsigned int)cvw) >> k) & 1u;                         \
    unsigned int ovb = ((((unsigned int)(cvw >> 1)) >> k) & 1u) << 31;          \
    unsigned int s2 = s1v + cin;                                                \
    unsigned int outv = ((s2 ^ AXG) >> 1) | ovb;                                \
    unsigned int rtP = ((((unsigned int)(mlo_o >> 1)) >> k) & 1u) << 31;        \
    crp = cin | rtP;                                                            \
    prevU = outv;

// ---------------- Stage 4: speculative-chunk tracker ----------------
// Phase 1: 16 chunks solve in parallel with prev = S_static (lower bound),
// writing spec to Osp; first 8 spec rows also to LDS; last spec row kept in a
// register.  Phase 2: sequential fixup with NO global access on the serial
// turn: spec from LDS/regs, boundary row = p1last (converged) or prevU (full
// depth), busy-poll handoff.
__global__ __launch_bounds__(1024, 1)
void k_track(const unsigned int* __restrict__ Sp,
             const unsigned int* __restrict__ Wp,
             const unsigned int* __restrict__ St,
             unsigned int* __restrict__ Osp) {
    __shared__ unsigned int ringW[NW][8][32];
    __shared__ unsigned int ringS[NW][8][32];
    __shared__ unsigned int ringT[NW][8][32];
    __shared__ unsigned int arrO[NW][8][32];      // first 8 spec rows per chunk
    __shared__ unsigned int prevRowLds[NW][32];
    __shared__ unsigned int fixedUpTo;

    const int tid = threadIdx.x;
    const int c = tid >> 6;
    const int lane = tid & 63;
    const int k = lane & 31;
    const int r0 = c * CH + 1;

    if (tid == 0) fixedUpTo = 0u;
    if (c == 0 && lane < 32) Osp[k] = 0u;                   // out row 0 = 0
    if (c == NW - 1 && lane < 32) Osp[1023 * 32 + k] = 0u;  // out row 1023 = 0

    // ---- phase 1: speculative solve ----
    for (int g = 0; g < 3; ++g) {
        int row = r0 + 2 * g;
        dma4(Wp + row * 32 + lane, &ringW[c][(2 * g) & 7][0]);
        dma4(Sp + row * 32 + lane, &ringS[c][(2 * g) & 7][0]);
        dma4(St + row * 32 + lane, &ringT[c][(2 * g) & 7][0]);
    }
    unsigned int prevU = Sp[(r0 - 1) * 32 + k];      // static lower bound
    unsigned int crp;
    {
        unsigned long long mh = __ballot((prevU >> 31) != 0u);
        unsigned long long ml = __ballot((prevU & 1u) != 0u);
        crp = ((((unsigned int)(mh << 1)) >> k) & 1u)
            | (((((unsigned int)(ml >> 1)) >> k) & 1u) << 31);
    }
    #pragma unroll 1
    for (int t = 0; t < 32; ++t) {
        if (t < 29) {
            int row = r0 + 2 * (t + 3);
            dma4(Wp + row * 32 + lane, &ringW[c][(2 * t + 6) & 7][0]);
            dma4(Sp + row * 32 + lane, &ringS[c][(2 * t + 6) & 7][0]);
            dma4(St + row * 32 + lane, &ringT[c][(2 * t + 6) & 7][0]);
        }
        asm volatile("s_waitcnt vmcnt(9)" ::: "memory");
        #pragma unroll
        for (int j = 0; j < 2; ++j) {
            int r = r0 + 2 * t + j;
            int sl = (2 * t + j) & 7;
            unsigned int Wv = ringW[c][sl][k];
            unsigned int Sv = ringS[c][sl][k];
            unsigned int Tv = ringT[c][sl][k];
            {
                CHAIN_STEP(Wv, Sv, Tv)
                if (r <= 1022) Osp[r * 32 + k] = outv;
                int d2 = 2 * t + j;
                if (d2 < 8) arrO[c][d2][k] = outv;   // LDS spec cache
            }
        }
    }
    unsigned int p1last = prevU;    // spec value of row r0+63 (true if converged)

    __syncthreads();   // spec complete + visible (barrier drains vm/lgkm)

    // ---- phase 2 prestage: statics rows r0..r0+7 back into the ring ----
    for (int g = 0; g < 4; ++g) {
        int row = r0 + 2 * g;
        dma4(Wp + row * 32 + lane, &ringW[c][2 * g][0]);
        dma4(Sp + row * 32 + lane, &ringS[c][2 * g][0]);
        dma4(St + row * 32 + lane, &ringT[c][2 * g][0]);
    }
    asm volatile("s_waitcnt vmcnt(0)" ::: "memory");

    unsigned int bd = p1last;
    if (c > 0) {
        while (*((volatile unsigned int*)&fixedUpTo) != (unsigned int)c) { }
        asm volatile("" ::: "memory");
        prevU = prevRowLds[c][k];                    // true last row of chunk c-1
        {
            unsigned long long mh = __ballot((prevU >> 31) != 0u);
            unsigned long long ml = __ballot((prevU & 1u) != 0u);
            crp = ((((unsigned int)(mh << 1)) >> k) & 1u)
                | (((((unsigned int)(ml >> 1)) >> k) & 1u) << 31);
        }
        bool converged = false;
        #pragma unroll 1
        for (int d = 0; d < CH; ++d) {
            int r = r0 + d;
            if (r > 1022) break;
            unsigned int Wv, Sv, Tv, spec;
            if (d < 8) { Wv = ringW[c][d][k]; Sv = ringS[c][d][k]; Tv = ringT[c][d][k];
                         spec = arrO[c][d][k]; }
            else       { Wv = Wp[r * 32 + k]; Sv = Sp[r * 32 + k]; Tv = St[r * 32 + k];
                         spec = Osp[r * 32 + k]; }
            {
                CHAIN_STEP(Wv, Sv, Tv)
                unsigned long long df = __ballot(outv != spec);
                if ((df & 0xFFFFFFFFull) == 0ull) { converged = true; break; }
                Osp[r * 32 + k] = outv;
            }
        }
        bd = converged ? p1last : prevU;   // true row r0+63 either way
    }
    // deposit true boundary row for the next chunk, then publish turn
    if (c < NW - 1) prevRowLds[c + 1][k] = bd;
    asm volatile("s_waitcnt lgkmcnt(0)" ::: "memory");
    if (lane == 0) *((volatile unsigned int*)&fixedUpTo) = (unsigned int)(c + 1);
}

// ---------------- Stage 5: unpack bits -> float ----------------
__global__ void k_unpack(const unsigned int* __restrict__ Osp,
                         float* __restrict__ out) {
    int idx = blockIdx.x * blockDim.x + threadIdx.x;
    if (idx >= NPIX) return;
    out[idx] = ((Osp[idx >> 5] >> (idx & 31)) & 1u) ? 1.f : 0.f;
}

extern "C" void kernel_launch(void* const* d_in, const int* in_sizes, int n_in,
                              void* d_out, int out_size, void* d_ws, size_t ws_size,
                              hipStream_t stream) {
    const float* x = (const float*)d_in[0];
    float* out = (float*)d_out;
    char* ws = (char*)d_ws;

    unsigned long long* Sp = (unsigned long long*)(ws);
    unsigned long long* Wp = (unsigned long long*)(ws + 128u * 1024u);
    unsigned int*       St = (unsigned int*)(ws + 256u * 1024u);
    unsigned int*      Osp = (unsigned int*)(ws + 384u * 1024u);

    k_fused<<<1024, 256, 0, stream>>>(x, Sp, Wp);
    k_prep2<<<128, 256, 0, stream>>>((const unsigned int*)Sp, St);
    k_track<<<1, 1024, 0, stream>>>((const unsigned int*)Sp, (const unsigned int*)Wp,
                                    (const unsigned int*)St, Osp);
    k_unpack<<<4096, 256, 0, stream>>>((const unsigned int*)Osp, out);
}